// Round 3
// 66.249 us; speedup vs baseline: 1.0298x; 1.0298x over previous
//
#include <hip/hip_runtime.h>
#include <math.h>

// ROI max pooling, TF-style bin mapping (see reference):
//   hs = (int)(H*roi[0]) (truncate), sh = max((he-hs)/7, 1)
//   bin i<6 rows: [hs+i*sh, min(hs+(i+1)*sh, he));  bin 6: [hs+6*sh, he)
// Shapes fixed by setup_inputs(): fm (2,50,50,256) f32, rois (2,100,4) f32,
// out (2,100,7,7,256) f32.
//
// R3 (3rd submit; two prior attempts died to container-acquisition infra
// failures, kernel never ran): occupancy fix — R2 used single-wave
// (64-thread) workgroups; CDNA caps resident workgroups/CU at 16, so 1-wave
// blocks top out at 16 waves/CU (50% of the 32-wave capacity) in a purely
// latency-bound kernel. Pack 4 cells (4 waves) per 256-thread workgroup ->
// up to 32 waves/CU and 4x fewer dispatch packets (2450 blocks). Chunked-8
// load pipeline kept (8 outstanding global_load_dwordx4 per waitcnt);
// full-chunk fast path split from the predicated tail (n is wave-uniform so
// tail predicates compile to scalar branches).
// Lane c holds channels 4c..4c+3 (64 lanes x float4 = 256 ch = 1 KiB/wave
// per position, ideal coalescing).

#define PH 7
#define PW 7
#define B_ 2
#define H_ 50
#define W_ 50
#define C_ 256
#define R_ 100

#define CHUNK 8
#define WPB 4   // waves (= output cells) per 256-thread workgroup

__global__ __launch_bounds__(256) void ROIPoolingLayer_33071248179308_kernel(
    const float* __restrict__ fm,    // (B,H,W,C)
    const float* __restrict__ rois,  // (B,R,4)
    float* __restrict__ out)         // (B,R,PH,PW,C)
{
    const int wave = threadIdx.x >> 6;
    const int lane = threadIdx.x & 63;
    const int cellFlat = blockIdx.x * WPB + wave;   // 0..9799 (2450*4 == 9800 exact)
    const int cell   = cellFlat % (PH * PW);
    const int roiIdx = cellFlat / (PH * PW);        // b*R + r
    const int b      = roiIdx / R_;
    const int i      = cell / PW;
    const int j      = cell % PW;

    // One 16B load for the whole ROI descriptor (wave-uniform address).
    const float4 roi = *(const float4*)(rois + (size_t)roiIdx * 4);

    // Truncating casts match jnp astype(int32) for non-negative values.
    const int hs = (int)((float)H_ * roi.x);
    const int ws = (int)((float)W_ * roi.y);
    const int he = (int)((float)H_ * roi.z);
    const int we = (int)((float)W_ * roi.w);
    const int sh = max((he - hs) / PH, 1);
    const int sw = max((we - ws) / PW, 1);

    const int y0 = hs + i * sh;
    const int y1 = (i == PH - 1) ? he : min(hs + (i + 1) * sh, he);
    const int x0 = ws + j * sw;
    const int x1 = (j == PW - 1) ? we : min(ws + (j + 1) * sw, we);

    const int bw = x1 - x0;
    const int bh = y1 - y0;
    int n = (bw > 0 && bh > 0) ? bh * bw : 0;

    const int c = lane * 4;    // 64 lanes x 4 channels = 256 = C_

    float4 m = make_float4(-INFINITY, -INFINITY, -INFINITY, -INFINITY);

    // Incremental position walker over the bin, row-major.
    int x = x0;
    const float* p = fm + ((size_t)b * H_ * W_ + (size_t)y0 * W_ + x0) * C_ + c;
    const ptrdiff_t row_skip = (ptrdiff_t)(W_ - bw) * C_;  // jump to next row start

    // Full chunks: 8 loads issued back-to-back (8 in flight per waitcnt).
    while (n >= CHUNK) {
        float4 buf[CHUNK];
#pragma unroll
        for (int t = 0; t < CHUNK; ++t) {
            buf[t] = *(const float4*)p;
            p += C_;
            if (++x == x1) { x = x0; p += row_skip; }
        }
#pragma unroll
        for (int t = 0; t < CHUNK; ++t) {
            m.x = fmaxf(m.x, buf[t].x);
            m.y = fmaxf(m.y, buf[t].y);
            m.z = fmaxf(m.z, buf[t].z);
            m.w = fmaxf(m.w, buf[t].w);
        }
        n -= CHUNK;
    }

    // Tail (n < CHUNK). n is wave-uniform -> scalar-branch predication.
    if (n > 0) {
        float4 buf[CHUNK];
#pragma unroll
        for (int t = 0; t < CHUNK; ++t) {
            if (t < n) {
                buf[t] = *(const float4*)p;
                p += C_;
                if (++x == x1) { x = x0; p += row_skip; }
            }
        }
#pragma unroll
        for (int t = 0; t < CHUNK; ++t) {
            if (t < n) {
                m.x = fmaxf(m.x, buf[t].x);
                m.y = fmaxf(m.y, buf[t].y);
                m.z = fmaxf(m.z, buf[t].z);
                m.w = fmaxf(m.w, buf[t].w);
            }
        }
    }

    *(float4*)(out + (size_t)cellFlat * C_ + c) = m;
}

extern "C" void kernel_launch(void* const* d_in, const int* in_sizes, int n_in,
                              void* d_out, int out_size, void* d_ws, size_t ws_size,
                              hipStream_t stream) {
    const float* fm   = (const float*)d_in[0];
    const float* rois = (const float*)d_in[1];
    float* out        = (float*)d_out;

    const int nblocks = (B_ * R_ * PH * PW) / WPB;  // 2450
    ROIPoolingLayer_33071248179308_kernel<<<nblocks, 256, 0, stream>>>(fm, rois, out);
}